// Round 4
// baseline (87.224 us; speedup 1.0000x reference)
//
#include <hip/hip_runtime.h>

// Shapes fixed by the reference:
//   x_LL : (8, 32, 128, 128)      f32
//   x    : (8, 4, 32, 128, 128)   f32  (channel 0 unused)
//   y    : (8, 32, 256, 256)      f32
//   out  : (8, 160, 256, 256)     f32  = cat(LL, LH, HL, HH, y) on axis 1
//
// out[b, sel*32+d, 2i+p, 2j+q] = src[b, d, i, j] * K[sel][p][q]   (sel<4)
// out[b, 128+d,    h,    w   ] = y[b, d, h, w]                    (sel==4)
//
// One wave = one (b, sel, d, i-pair) unit:
//   upsample: 2 independent float2 row-loads (src rows 2k, 2k+1) issued
//             back-to-back (read MLP=2), then 4x float4 stores covering
//             output rows 4k..4k+3 = 4 KB contiguous per wave.
//   y-copy:   4 float4 loads + 4 float4 stores (rows 4k..4k+3).
// All loads/stores fully coalesced; nontemporal (pure streaming, no reuse).

#define DD 32
#define H_IN 128
#define W_IN 128
#define H2 256
#define W2 256

typedef float f32x4 __attribute__((ext_vector_type(4)));
typedef float f32x2 __attribute__((ext_vector_type(2)));

__global__ __launch_bounds__(256) void haar_iwt_cat_kernel(
    const float* __restrict__ xLL,
    const float* __restrict__ x,
    const float* __restrict__ y,
    float*       __restrict__ out)
{
    const unsigned tid  = threadIdx.x;
    const unsigned lane = tid & 63u;
    // wave-unit u = (((b*5 + sel)*32 + d)*64 + k), k = source-row pair index
    const unsigned u = blockIdx.x * 4u + (tid >> 6);

    const unsigned k = u & 63u;          // i-pair: src rows 2k,2k+1; out rows 4k..4k+3
    unsigned t = u >> 6;                 // (b*5 + sel)*32 + d
    const unsigned d = t & (DD - 1u);
    t >>= 5;                             // b*5 + sel, < 40
    const unsigned b   = t / 5u;
    const unsigned sel = t - b * 5u;

    const unsigned c = (sel == 4u) ? (128u + d) : (sel * 32u + d);
    float* orow = out + (((size_t)(b * 160u + c) * H2 + 4u * k) * W2);
    f32x4* o0 = ((f32x4*)(orow        )) + lane;
    f32x4* o1 = ((f32x4*)(orow +   W2 )) + lane;
    f32x4* o2 = ((f32x4*)(orow + 2*W2 )) + lane;
    f32x4* o3 = ((f32x4*)(orow + 3*W2 )) + lane;

    if (sel == 4u) {
        const float* yrow = y + (((size_t)(b * DD + d) * H2 + 4u * k) * W2);
        const f32x4 v0 = __builtin_nontemporal_load(((const f32x4*)(yrow       )) + lane);
        const f32x4 v1 = __builtin_nontemporal_load(((const f32x4*)(yrow +  W2)) + lane);
        const f32x4 v2 = __builtin_nontemporal_load(((const f32x4*)(yrow + 2*W2)) + lane);
        const f32x4 v3 = __builtin_nontemporal_load(((const f32x4*)(yrow + 3*W2)) + lane);
        __builtin_nontemporal_store(v0, o0);
        __builtin_nontemporal_store(v1, o1);
        __builtin_nontemporal_store(v2, o2);
        __builtin_nontemporal_store(v3, o3);
        return;
    }

    const float* srow = (sel == 0u)
        ? xLL + ((size_t)(b * DD + d) * H_IN + 2u * k) * W_IN
        : x   + ((size_t)((b * 4u + sel) * DD + d) * H_IN + 2u * k) * W_IN;
    // two independent row loads, both in flight before use
    const f32x2 va = __builtin_nontemporal_load(((const f32x2*)(srow       )) + lane);
    const f32x2 vb = __builtin_nontemporal_load(((const f32x2*)(srow + W_IN)) + lane);

    // K[sel] rows: (k00,k01) for p=0, (k10,k11) for p=1
    float k00, k01, k10, k11;
    switch (sel) {
        case 0u: k00 =  0.5f; k01 =  0.5f; k10 =  0.5f; k11 =  0.5f; break; // LL
        case 1u: k00 = -0.5f; k01 =  0.5f; k10 = -0.5f; k11 =  0.5f; break; // LH
        case 2u: k00 = -0.5f; k01 = -0.5f; k10 =  0.5f; k11 =  0.5f; break; // HL
        default: k00 =  0.5f; k01 = -0.5f; k10 = -0.5f; k11 =  0.5f; break; // HH
    }

    f32x4 r0, r1, r2, r3;
    r0.x = va.x * k00; r0.y = va.x * k01; r0.z = va.y * k00; r0.w = va.y * k01;
    r1.x = va.x * k10; r1.y = va.x * k11; r1.z = va.y * k10; r1.w = va.y * k11;
    r2.x = vb.x * k00; r2.y = vb.x * k01; r2.z = vb.y * k00; r2.w = vb.y * k01;
    r3.x = vb.x * k10; r3.y = vb.x * k11; r3.z = vb.y * k10; r3.w = vb.y * k11;
    __builtin_nontemporal_store(r0, o0);
    __builtin_nontemporal_store(r1, o1);
    __builtin_nontemporal_store(r2, o2);
    __builtin_nontemporal_store(r3, o3);
}

extern "C" void kernel_launch(void* const* d_in, const int* in_sizes, int n_in,
                              void* d_out, int out_size, void* d_ws, size_t ws_size,
                              hipStream_t stream) {
    const float* xLL = (const float*)d_in[0];
    const float* x   = (const float*)d_in[1];
    const float* y   = (const float*)d_in[2];
    float*       out = (float*)d_out;

    // wave-units: 8 b * 5 sel * 32 d * 64 pairs = 81,920; 4 waves per block
    const int grid  = 81920 / 4;   // 20,480 blocks
    const int block = 256;
    haar_iwt_cat_kernel<<<grid, block, 0, stream>>>(xLL, x, y, out);
}